// Round 4
// baseline (3902.816 us; speedup 1.0000x reference)
//
#include <hip/hip_runtime.h>

#define NN 1024
#define BB 32
#define DD 128
#define EPSF 1e-6f
#define CAP 16384
#define NNNN ((size_t)NN * NN)

typedef __bf16 bf16x8 __attribute__((ext_vector_type(8)));
typedef float  f32x4  __attribute__((ext_vector_type(4)));
typedef unsigned short u16x8 __attribute__((ext_vector_type(8)));

__device__ __forceinline__ float bf2f(unsigned short u) {
  union { unsigned int i; float f; } v; v.i = ((unsigned int)u) << 16; return v.f;
}
__device__ __forceinline__ unsigned short f2bf(float f) {
  union { float f; unsigned int i; } v; v.f = f;
  unsigned int r = v.i + 0x7fffu + ((v.i >> 16) & 1u);
  return (unsigned short)(r >> 16);
}

// ---------------- convert / transpose kernels ----------------

__global__ __launch_bounds__(256) void convert_wp(const float* __restrict__ src,
    unsigned short* __restrict__ Wp, unsigned short* __restrict__ WpT) {
  __shared__ float tile[64][65];
  const int b = blockIdx.z;
  const int c0 = blockIdx.x * 64, r0 = blockIdx.y * 64;
  const int t = threadIdx.x;
  const int rr = t >> 3, cb = (t & 7) * 8;
  const size_t base = (size_t)b * NNNN;
#pragma unroll
  for (int p = 0; p < 2; ++p) {
    const int r = rr + p * 32;
    const float* srow = src + base + (size_t)(r0 + r) * NN + c0 + cb;
    f32x4 v0 = *(const f32x4*)srow;
    f32x4 v1 = *(const f32x4*)(srow + 4);
    u16x8 w;
#pragma unroll
    for (int j = 0; j < 4; ++j) { w[j] = f2bf(v0[j]); w[4 + j] = f2bf(v1[j]); }
    *(u16x8*)(Wp + base + (size_t)(r0 + r) * NN + c0 + cb) = w;
#pragma unroll
    for (int j = 0; j < 4; ++j) { tile[r][cb + j] = v0[j]; tile[r][cb + 4 + j] = v1[j]; }
  }
  __syncthreads();
#pragma unroll
  for (int p = 0; p < 2; ++p) {
    const int r = rr + p * 32;
    u16x8 w;
#pragma unroll
    for (int j = 0; j < 8; ++j) w[j] = f2bf(tile[cb + j][r]);
    *(u16x8*)(WpT + base + (size_t)(c0 + r) * NN + r0 + cb) = w;
  }
}

__global__ __launch_bounds__(256) void convert_x(const float* __restrict__ x,
    unsigned short* __restrict__ xT) {
  __shared__ float tile[32][33];
  const int b = blockIdx.z;
  const int d0 = blockIdx.x * 32, n0 = blockIdx.y * 32;
  const int tx = threadIdx.x, ty = threadIdx.y;
#pragma unroll
  for (int s = 0; s < 4; ++s) {
    int rr = ty + s * 8;
    tile[rr][tx] = x[(size_t)b * NN * DD + (size_t)(n0 + rr) * DD + d0 + tx];
  }
  __syncthreads();
#pragma unroll
  for (int s = 0; s < 4; ++s) {
    int rr = ty + s * 8;
    xT[(size_t)b * DD * NN + (size_t)(d0 + rr) * NN + n0 + tx] = f2bf(tile[tx][rr]);
  }
}

// adj -> mcode bit0 (= adj[j,i]==1 at [i,j]), adj_bf, adjT_bf
__global__ __launch_bounds__(256) void mask0cvt(const float* __restrict__ adj,
    unsigned char* __restrict__ mcode, unsigned short* __restrict__ adjbf,
    unsigned short* __restrict__ adjTbf) {
  __shared__ float tile[32][33];
  const int i0 = blockIdx.x * 32, j0 = blockIdx.y * 32;
  const int tx = threadIdx.x, ty = threadIdx.y;
#pragma unroll
  for (int s = 0; s < 4; ++s) {
    int rr = ty + s * 8;
    float v = adj[(size_t)(j0 + rr) * NN + i0 + tx];
    adjbf[(size_t)(j0 + rr) * NN + i0 + tx] = f2bf(v);
    tile[rr][tx] = v;
  }
  __syncthreads();
#pragma unroll
  for (int s = 0; s < 4; ++s) {
    int rr = ty + s * 8;
    float v = tile[tx][rr];
    adjTbf[(size_t)(i0 + rr) * NN + j0 + tx] = f2bf(v);
    mcode[(size_t)(i0 + rr) * NN + j0 + tx] = (v == 1.0f) ? 1 : 0;
  }
}

// sum 4 K-split partials (exact ints) -> A2 bf16, A2T bf16, mcode bit1 where ==1
__global__ __launch_bounds__(256) void scan_a2(const float* __restrict__ P,
    unsigned short* __restrict__ A2, unsigned short* __restrict__ A2T,
    unsigned char* __restrict__ mcode) {
  __shared__ float tile[32][33];
  const int m0 = blockIdx.x * 32, n0 = blockIdx.y * 32;
  const int tx = threadIdx.x, ty = threadIdx.y;
#pragma unroll
  for (int s = 0; s < 4; ++s) {
    int rr = ty + s * 8;
    size_t idx = (size_t)(m0 + rr) * NN + n0 + tx;
    float v = P[idx] + P[NNNN + idx] + P[2 * NNNN + idx] + P[3 * NNNN + idx];
    A2[idx] = f2bf(v);
    tile[rr][tx] = v;
  }
  __syncthreads();
#pragma unroll
  for (int s = 0; s < 4; ++s) {
    int rr = ty + s * 8;
    float v = tile[tx][rr];
    A2T[(size_t)(n0 + rr) * NN + m0 + tx] = f2bf(v);
    if (v == 1.0f) mcode[(size_t)(n0 + rr) * NN + m0 + tx] |= 2;
  }
}

// sum 4 partials of A^4; record entries (m<<16)|n where ==1.0
__global__ __launch_bounds__(256) void scan_a4(const float* __restrict__ P,
    unsigned int* __restrict__ entries, int* __restrict__ nnz) {
  size_t e = (size_t)blockIdx.x * 256 + threadIdx.x;
  float v = P[e] + P[NNNN + e] + P[2 * NNNN + e] + P[3 * NNNN + e];
  if (v == 1.0f) {
    int idx = atomicAdd(nnz, 1);
    if (idx < CAP) entries[idx] = ((unsigned)(e >> 10) << 16) | (unsigned)(e & 1023);
  }
}

// ---------------- distance-2 register-prefetch pipelined MFMA GEMM ----------------
// C[m,n] = sum_k A[m,k]*B[n,k]. Double LDS buffer, 2 register sets (loads in
// flight ~2 iterations), 1 raw barrier/iter, no global_load_lds (legalizer-safe).
#define BM 128
#define BN 128
#define BK 32

struct EpiWcomb {  // mask2-gated bf16 write
  const unsigned char* mc;
  unsigned short* out;
  __device__ __forceinline__ void operator()(int b, int ks, int i, int j, float v) const {
    size_t idx = (size_t)i * NN + j;
    out[(size_t)b * NNNN + idx] = (mc[idx] & 2) ? f2bf(v) : (unsigned short)0;
  }
};

struct EpiSqPart {  // K-split partial, plain store
  float* buf;
  __device__ __forceinline__ void operator()(int b, int ks, int i, int j, float v) const {
    buf[(size_t)ks * NNNN + (size_t)i * NN + j] = v;
  }
};

struct EpiAggPart {  // 2-way K-split partials (p0 = d_out, p1 = ws)
  float* p0;
  float* p1;
  __device__ __forceinline__ void operator()(int b, int ks, int i, int d, float v) const {
    (ks ? p1 : p0)[(size_t)b * NN * DD + (size_t)i * DD + d] = v;
  }
};

#define LGKM_BARRIER() do { \
  asm volatile("s_waitcnt lgkmcnt(0)" ::: "memory"); \
  __builtin_amdgcn_s_barrier(); \
  asm volatile("" ::: "memory"); } while (0)

template <int MW, bool COMB, typename Epi>
__global__ __launch_bounds__(256, MW) void gemm_pipe(
    const unsigned short* __restrict__ Ap, size_t sA,
    const unsigned short* __restrict__ WtP, const unsigned char* __restrict__ McP,
    const unsigned short* __restrict__ Bp, size_t sB,
    int swz, int ksN, int nit, Epi epi) {
  __shared__ __align__(16) unsigned short As[2 * BM * BK];
  __shared__ __align__(16) unsigned short Bs[2 * BN * BK];
  const int z = blockIdx.z;
  const int b = z / ksN, ks = z - b * ksN;
  const int kbase = ks * nit * BK;
  int bx = blockIdx.x, by = blockIdx.y;
  if (swz) {  // 2x4 rect for per-XCD L2 locality
    int lin = bx + (by << 3);
    int r = lin & 7, s = lin >> 3;
    bx = ((r & 3) << 1) | (s & 1);
    by = ((r >> 2) << 2) | (s >> 1);
  }
  const int tm = bx * BM, tn = by * BN;
  const unsigned short* Ab = Ap + (size_t)b * sA;
  const unsigned short* Bb = Bp + (size_t)b * sB;
  const unsigned short* Wb = COMB ? (WtP + (size_t)b * sA) : nullptr;
  const int tid = threadIdx.x;
  const int w = tid >> 6, l = tid & 63;
  const int lr = l >> 2, lc = l & 3;
  const int fr = l & 15, quad = l >> 4;
  const int moff = (w & 1) * 64, noff = (w >> 1) * 64;
  const int r0 = w * 16 + lr, r1 = (w + 4) * 16 + lr;
  const int kc0 = lc ^ ((r0 >> 1) & 3), kc1 = lc ^ ((r1 >> 1) & 3);
  const size_t ao0 = (size_t)(tm + r0) * NN + kbase + kc0 * 8;
  const size_t ao1 = (size_t)(tm + r1) * NN + kbase + kc1 * 8;
  const size_t bo0 = (size_t)(tn + r0) * NN + kbase + kc0 * 8;
  const size_t bo1 = (size_t)(tn + r1) * NN + kbase + kc1 * 8;
  const int ls0 = r0 * BK + lc * 8, ls1 = r1 * BK + lc * 8;

  f32x4 acc[4][4];
#pragma unroll
  for (int mi = 0; mi < 4; ++mi)
#pragma unroll
    for (int ni = 0; ni < 4; ++ni) acc[mi][ni] = (f32x4){0.f, 0.f, 0.f, 0.f};

  u16x8 rA[2][2], rB[2][2], rW[2][2];
  unsigned long long rM[2][2];

  auto load = [&](int s, int kt) {
    size_t kk = (size_t)kt * BK;
    rA[s][0] = *(const u16x8*)(Ab + ao0 + kk);
    rA[s][1] = *(const u16x8*)(Ab + ao1 + kk);
    rB[s][0] = *(const u16x8*)(Bb + bo0 + kk);
    rB[s][1] = *(const u16x8*)(Bb + bo1 + kk);
    if constexpr (COMB) {
      rW[s][0] = *(const u16x8*)(Wb + ao0 + kk);
      rW[s][1] = *(const u16x8*)(Wb + ao1 + kk);
      rM[s][0] = *(const unsigned long long*)(McP + ao0 + kk);
      rM[s][1] = *(const unsigned long long*)(McP + ao1 + kk);
    }
  };
  auto wr = [&](int s) {
    unsigned short* Ad = As + s * (BM * BK);
    unsigned short* Bd = Bs + s * (BN * BK);
    if constexpr (COMB) {
#pragma unroll
      for (int g = 0; g < 2; ++g) {
        u16x8 f;
#pragma unroll
        for (int j = 0; j < 8; ++j) {
          float sv = bf2f(rA[s][g][j]);
          if ((rM[s][g] >> (8 * j)) & 1ull) sv += bf2f(rW[s][g][j]);
          f[j] = f2bf(sv);
        }
        *(u16x8*)(Ad + (g ? ls1 : ls0)) = f;
      }
    } else {
      *(u16x8*)(Ad + ls0) = rA[s][0];
      *(u16x8*)(Ad + ls1) = rA[s][1];
    }
    *(u16x8*)(Bd + ls0) = rB[s][0];
    *(u16x8*)(Bd + ls1) = rB[s][1];
  };
  auto compute = [&](int par) {
    const unsigned short* Ad = As + par * (BM * BK);
    const unsigned short* Bd = Bs + par * (BN * BK);
    bf16x8 af[4], bfr[4];
#pragma unroll
    for (int mi = 0; mi < 4; ++mi) {
      int r = moff + mi * 16 + fr;
      int kc = quad ^ ((r >> 1) & 3);
      af[mi] = *(const bf16x8*)(Ad + r * BK + kc * 8);
    }
#pragma unroll
    for (int ni = 0; ni < 4; ++ni) {
      int r = noff + ni * 16 + fr;
      int kc = quad ^ ((r >> 1) & 3);
      bfr[ni] = *(const bf16x8*)(Bd + r * BK + kc * 8);
    }
#pragma unroll
    for (int mi = 0; mi < 4; ++mi)
#pragma unroll
      for (int ni = 0; ni < 4; ++ni)
        acc[mi][ni] = __builtin_amdgcn_mfma_f32_16x16x32_bf16(af[mi], bfr[ni], acc[mi][ni], 0, 0, 0);
  };

  // prologue: LDS0<-tile0, set1<-tile1 (in flight), set0<-tile2 (in flight)
  load(0, 0);
  load(1, 1);
  wr(0);
  load(0, 2);
  LGKM_BARRIER();
#pragma unroll 1
  for (int kt = 0; kt < nit - 2; ++kt) {
    compute(kt & 1);
    const int s = (kt + 1) & 1;
    wr(s);                               // regs loaded 2 iters ago
    if (kt < nit - 3) load(s, kt + 3);   // keep distance-2 in flight
    LGKM_BARRIER();
  }
  compute((nit - 2) & 1);
  wr((nit - 1) & 1);
  LGKM_BARRIER();
  compute((nit - 1) & 1);

  // C/D layout: col = lane&15, row = quad*4 + reg
#pragma unroll
  for (int mi = 0; mi < 4; ++mi)
#pragma unroll
    for (int ni = 0; ni < 4; ++ni)
#pragma unroll
      for (int t = 0; t < 4; ++t)
        epi(b, ks, tm + moff + mi * 16 + quad * 4 + t, tn + noff + ni * 16 + fr, acc[mi][ni][t]);
}

// ---------------- gated hop-2 sparse fixup (expected: nnz==0, exits) ----------------
__global__ __launch_bounds__(256) void hop2_fix(const unsigned short* __restrict__ Wp,
    const unsigned short* __restrict__ WpT, const int* __restrict__ nnz,
    const unsigned int* __restrict__ entries, unsigned short* __restrict__ WcombT) {
  int n = *nnz;
  if (n > CAP) n = CAP;
  if (n == 0) return;
  __shared__ float rbuf[256];
  const int b = blockIdx.x;
  const size_t bnn = (size_t)b * NNNN;
  for (int e = blockIdx.y; e < n; e += gridDim.y) {
    unsigned int ent = entries[e];
    int j = ent >> 16, i = ent & 0xFFFF;
    float s = 0.f;
    for (int k = threadIdx.x; k < NN; k += 256) {
      float u = 0.f, v = 0.f;
      const unsigned short* wj  = Wp  + bnn + (size_t)j * NN;
      const unsigned short* wtk = WpT + bnn + (size_t)k * NN;
      const unsigned short* wk  = Wp  + bnn + (size_t)k * NN;
      const unsigned short* wti = WpT + bnn + (size_t)i * NN;
      for (int t = 0; t < NN; ++t) {
        u += bf2f(wj[t]) * bf2f(wtk[t]);
        v += bf2f(wk[t]) * bf2f(wti[t]);
      }
      s += u * v;
    }
    rbuf[threadIdx.x] = s;
    __syncthreads();
    for (int off = 128; off > 0; off >>= 1) {
      if (threadIdx.x < off) rbuf[threadIdx.x] += rbuf[threadIdx.x + off];
      __syncthreads();
    }
    if (threadIdx.x == 0) {
      size_t idx = bnn + (size_t)i * NN + j;
      WcombT[idx] = f2bf(bf2f(WcombT[idx]) + rbuf[0]);
    }
    __syncthreads();
  }
}

// ---------------- fused (sum 2 agg partials) + Linear + residual + LayerNorm ----------------
#define FROWS 16
__global__ __launch_bounds__(256) void fused_out(const float* __restrict__ a0p,
    const float* __restrict__ a1p, const float* __restrict__ x,
    const float* __restrict__ W, const float* __restrict__ bias,
    const float* __restrict__ g2, const float* __restrict__ bsh,
    float* __restrict__ out) {
  __shared__ unsigned short Wl[128 * 136];
  __shared__ float ar[256];
  __shared__ float wred[8];
  const int tid = threadIdx.x;
  for (int e = tid; e < 16384; e += 256) Wl[(e >> 7) * 136 + (e & 127)] = f2bf(W[e]);
  const int half = tid >> 7, o = tid & 127;
  const int w = tid >> 6, lane = tid & 63;
  const float bo = bias[o], go = g2[o], b2o = bsh[o];
  const size_t row0 = (size_t)blockIdx.x * FROWS;
  size_t rb = row0 * DD;
  float av = a0p[rb + tid] + a1p[rb + tid];   // prefetched row pair
  float xv = x[rb + tid];
  __syncthreads();  // Wl ready
  for (int rr = 0; rr < FROWS; rr += 2) {
    ar[tid] = av;
    const float xcur = xv;
    const size_t rbc = (row0 + rr) * DD;
    __syncthreads();  // ar ready
    if (rr + 2 < FROWS) {
      size_t rb2 = (row0 + rr + 2) * DD;
      av = a0p[rb2 + tid] + a1p[rb2 + tid];
      xv = x[rb2 + tid];
    }
    float hv = bo + xcur;
    const unsigned short* wrow = &Wl[o * 136];
    const float* arow = &ar[half * 128];
#pragma unroll
    for (int d8 = 0; d8 < 16; ++d8) {
      bf16x8 wv = *(const bf16x8*)(wrow + d8 * 8);
#pragma unroll
      for (int t = 0; t < 8; ++t) hv += (float)wv[t] * arow[d8 * 8 + t];
    }
    float s = hv, q = hv * hv;
#pragma unroll
    for (int off = 32; off > 0; off >>= 1) {
      s += __shfl_xor(s, off);
      q += __shfl_xor(q, off);
    }
    if (lane == 0) { wred[w] = s; wred[4 + w] = q; }
    __syncthreads();  // wred ready (also gates ar overwrite next iter)
    float st = wred[half * 2] + wred[half * 2 + 1];
    float qt = wred[4 + half * 2] + wred[4 + half * 2 + 1];
    float mean = st * (1.0f / 128.0f);
    float var = (qt - 128.0f * mean * mean) * (1.0f / 127.0f);
    var = fmaxf(var, 0.0f);
    float stdv = sqrtf(var);
    out[rbc + tid] = go * (hv - mean) / (stdv + EPSF) + b2o;
  }
}

// ---------------- launch ----------------
extern "C" void kernel_launch(void* const* d_in, const int* in_sizes, int n_in,
                              void* d_out, int out_size, void* d_ws, size_t ws_size,
                              hipStream_t stream) {
  (void)in_sizes; (void)n_in; (void)out_size; (void)ws_size;
  const float* x    = (const float*)d_in[0];
  const float* adjw = (const float*)d_in[1];
  const float* adj  = (const float*)d_in[2];
  const float* W    = (const float*)d_in[3];
  const float* bias = (const float*)d_in[4];
  const float* a2   = (const float*)d_in[5];
  const float* b2   = (const float*)d_in[6];
  float* out = (float*)d_out;

  char* ws = (char*)d_ws;
  const size_t MB = 1048576;
  unsigned short* Wp_bf   = (unsigned short*)(ws);             // 64 MB
  unsigned short* WpT_bf  = (unsigned short*)(ws + 64 * MB);   // 64 MB
  unsigned short* WcombT  = (unsigned short*)(ws + 128 * MB);  // 64 MB
  unsigned short* xT_bf   = (unsigned short*)(ws + 192 * MB);  // 8 MB
  unsigned short* adj_bf  = (unsigned short*)(ws + 200 * MB);  // 2 MB
  unsigned short* adjT_bf = (unsigned short*)(ws + 202 * MB);  // 2 MB
  unsigned short* A2_bf   = (unsigned short*)(ws + 204 * MB);  // 2 MB
  unsigned short* A2T_bf  = (unsigned short*)(ws + 206 * MB);  // 2 MB
  float* sqpart           = (float*)(ws + 208 * MB);           // 16 MB (4 partials)
  // agg partial 1 overlaps the adj/A2/sqpart region (all consumed before agg gemm)
  float* agg1             = (float*)(ws + 200 * MB);           // 16 MB
  unsigned char* mcode    = (unsigned char*)(ws + 224 * MB);   // 1 MB
  unsigned int* entries   = (unsigned int*)(ws + 225 * MB);    // 64 KB
  int* nnz2               = (int*)(ws + 226 * MB);             // 4 B
  float* agg0 = out;  // d_out doubles as agg partial 0

  hipMemsetAsync(nnz2, 0, 4, stream);

  dim3 blk32(32, 8, 1);
  convert_wp<<<dim3(16, 16, 32), 256, 0, stream>>>(adjw, Wp_bf, WpT_bf);
  convert_x<<<dim3(4, 32, 32), blk32, 0, stream>>>(x, xT_bf);
  mask0cvt<<<dim3(32, 32, 1), blk32, 0, stream>>>(adj, mcode, adj_bf, adjT_bf);

  // A^2: K-split 4, exact integer partials, plain stores
  gemm_pipe<3, false><<<dim3(8, 8, 4), 256, 0, stream>>>(
      adj_bf, (size_t)0, nullptr, nullptr, adjT_bf, (size_t)0, 0, 4, 8,
      EpiSqPart{sqpart});
  scan_a2<<<dim3(32, 32, 1), blk32, 0, stream>>>(sqpart, A2_bf, A2T_bf, mcode);
  // A^4: K-split 4 (A^2 ints < 256 exact in bf16)
  gemm_pipe<3, false><<<dim3(8, 8, 4), 256, 0, stream>>>(
      A2_bf, (size_t)0, nullptr, nullptr, A2T_bf, (size_t)0, 0, 4, 8,
      EpiSqPart{sqpart});
  scan_a4<<<dim3(4096, 1, 1), 256, 0, stream>>>(sqpart, entries, nnz2);

  // big batched gemm: WcombT = mask2 .* (Wp^2)^T
  gemm_pipe<3, false><<<dim3(8, 8, 32), 256, 0, stream>>>(
      WpT_bf, NNNN, nullptr, nullptr, Wp_bf, NNNN, 1, 1, NN / BK,
      EpiWcomb{mcode, WcombT});

  hop2_fix<<<dim3(32, 8, 1), 256, 0, stream>>>(Wp_bf, WpT_bf, nnz2, entries, WcombT);

  // agg = (WcombT + mask1^T.*WpT) @ x — K-split 2 partials (fold in staging)
  gemm_pipe<2, true><<<dim3(8, 1, 64), 256, 0, stream>>>(
      WcombT, NNNN, WpT_bf, mcode, xT_bf, (size_t)DD * NN, 0, 2, 16,
      EpiAggPart{agg0, agg1});

  fused_out<<<dim3(2048, 1, 1), 256, 0, stream>>>(agg0, agg1, x, W, bias, a2, b2, out);
}

// Round 5
// 476.863 us; speedup vs baseline: 8.1844x; 8.1844x over previous
//
#include <hip/hip_runtime.h>

#define NN 1024
#define BB 32
#define DD 128
#define EPSF 1e-6f
#define CAP 16384
#define NNNN ((size_t)NN * NN)

typedef __bf16 bf16x8 __attribute__((ext_vector_type(8)));
typedef float  f32x4  __attribute__((ext_vector_type(4)));
typedef unsigned short u16x8 __attribute__((ext_vector_type(8)));

__device__ __forceinline__ float bf2f(unsigned short u) {
  union { unsigned int i; float f; } v; v.i = ((unsigned int)u) << 16; return v.f;
}
__device__ __forceinline__ unsigned short f2bf(float f) {
  union { float f; unsigned int i; } v; v.f = f;
  unsigned int r = v.i + 0x7fffu + ((v.i >> 16) & 1u);
  return (unsigned short)(r >> 16);
}

// ---------------- convert / transpose kernels ----------------

__global__ __launch_bounds__(256) void convert_wp(const float* __restrict__ src,
    unsigned short* __restrict__ Wp, unsigned short* __restrict__ WpT) {
  __shared__ float tile[64][65];
  const int b = blockIdx.z;
  const int c0 = blockIdx.x * 64, r0 = blockIdx.y * 64;
  const int t = threadIdx.x;
  const int rr = t >> 3, cb = (t & 7) * 8;
  const size_t base = (size_t)b * NNNN;
#pragma unroll
  for (int p = 0; p < 2; ++p) {
    const int r = rr + p * 32;
    const float* srow = src + base + (size_t)(r0 + r) * NN + c0 + cb;
    f32x4 v0 = *(const f32x4*)srow;
    f32x4 v1 = *(const f32x4*)(srow + 4);
    u16x8 w;
#pragma unroll
    for (int j = 0; j < 4; ++j) { w[j] = f2bf(v0[j]); w[4 + j] = f2bf(v1[j]); }
    *(u16x8*)(Wp + base + (size_t)(r0 + r) * NN + c0 + cb) = w;
#pragma unroll
    for (int j = 0; j < 4; ++j) { tile[r][cb + j] = v0[j]; tile[r][cb + 4 + j] = v1[j]; }
  }
  __syncthreads();
#pragma unroll
  for (int p = 0; p < 2; ++p) {
    const int r = rr + p * 32;
    u16x8 w;
#pragma unroll
    for (int j = 0; j < 8; ++j) w[j] = f2bf(tile[cb + j][r]);
    *(u16x8*)(WpT + base + (size_t)(c0 + r) * NN + r0 + cb) = w;
  }
}

__global__ __launch_bounds__(256) void convert_x(const float* __restrict__ x,
    unsigned short* __restrict__ xT) {
  __shared__ float tile[32][33];
  const int b = blockIdx.z;
  const int d0 = blockIdx.x * 32, n0 = blockIdx.y * 32;
  const int tx = threadIdx.x, ty = threadIdx.y;
#pragma unroll
  for (int s = 0; s < 4; ++s) {
    int rr = ty + s * 8;
    tile[rr][tx] = x[(size_t)b * NN * DD + (size_t)(n0 + rr) * DD + d0 + tx];
  }
  __syncthreads();
#pragma unroll
  for (int s = 0; s < 4; ++s) {
    int rr = ty + s * 8;
    xT[(size_t)b * DD * NN + (size_t)(d0 + rr) * NN + n0 + tx] = f2bf(tile[tx][rr]);
  }
}

// adj -> mcode bit0 (= adj[j,i]==1 at [i,j]), adj_bf, adjT_bf
__global__ __launch_bounds__(256) void mask0cvt(const float* __restrict__ adj,
    unsigned char* __restrict__ mcode, unsigned short* __restrict__ adjbf,
    unsigned short* __restrict__ adjTbf) {
  __shared__ float tile[32][33];
  const int i0 = blockIdx.x * 32, j0 = blockIdx.y * 32;
  const int tx = threadIdx.x, ty = threadIdx.y;
#pragma unroll
  for (int s = 0; s < 4; ++s) {
    int rr = ty + s * 8;
    float v = adj[(size_t)(j0 + rr) * NN + i0 + tx];
    adjbf[(size_t)(j0 + rr) * NN + i0 + tx] = f2bf(v);
    tile[rr][tx] = v;
  }
  __syncthreads();
#pragma unroll
  for (int s = 0; s < 4; ++s) {
    int rr = ty + s * 8;
    float v = tile[tx][rr];
    adjTbf[(size_t)(i0 + rr) * NN + j0 + tx] = f2bf(v);
    mcode[(size_t)(i0 + rr) * NN + j0 + tx] = (v == 1.0f) ? 1 : 0;
  }
}

// sum 4 K-split partials (exact ints) -> A2 bf16, A2T bf16, mcode bit1 where ==1
__global__ __launch_bounds__(256) void scan_a2(const float* __restrict__ P,
    unsigned short* __restrict__ A2, unsigned short* __restrict__ A2T,
    unsigned char* __restrict__ mcode) {
  __shared__ float tile[32][33];
  const int m0 = blockIdx.x * 32, n0 = blockIdx.y * 32;
  const int tx = threadIdx.x, ty = threadIdx.y;
#pragma unroll
  for (int s = 0; s < 4; ++s) {
    int rr = ty + s * 8;
    size_t idx = (size_t)(m0 + rr) * NN + n0 + tx;
    float v = P[idx] + P[NNNN + idx] + P[2 * NNNN + idx] + P[3 * NNNN + idx];
    A2[idx] = f2bf(v);
    tile[rr][tx] = v;
  }
  __syncthreads();
#pragma unroll
  for (int s = 0; s < 4; ++s) {
    int rr = ty + s * 8;
    float v = tile[tx][rr];
    A2T[(size_t)(n0 + rr) * NN + m0 + tx] = f2bf(v);
    if (v == 1.0f) mcode[(size_t)(n0 + rr) * NN + m0 + tx] |= 2;
  }
}

// sum 4 partials of A^4; record entries (m<<16)|n where ==1.0
__global__ __launch_bounds__(256) void scan_a4(const float* __restrict__ P,
    unsigned int* __restrict__ entries, int* __restrict__ nnz) {
  size_t e = (size_t)blockIdx.x * 256 + threadIdx.x;
  float v = P[e] + P[NNNN + e] + P[2 * NNNN + e] + P[3 * NNNN + e];
  if (v == 1.0f) {
    int idx = atomicAdd(nnz, 1);
    if (idx < CAP) entries[idx] = ((unsigned)(e >> 10) << 16) | (unsigned)(e & 1023);
  }
}

// ---------------- distance-2 register-prefetch pipelined MFMA GEMM ----------------
// C[m,n] = sum_k A[m,k]*B[n,k]. Double LDS buffer, TWO NAMED register sets
// (compile-time selection — R4's dynamic-index arrays spilled to scratch),
// manually 2x-unrolled K-loop so LDS parity is a literal constant.
#define BM 128
#define BN 128
#define BK 32

struct EpiWcomb {  // mask2-gated bf16 write
  const unsigned char* mc;
  unsigned short* out;
  __device__ __forceinline__ void operator()(int b, int ks, int i, int j, float v) const {
    size_t idx = (size_t)i * NN + j;
    out[(size_t)b * NNNN + idx] = (mc[idx] & 2) ? f2bf(v) : (unsigned short)0;
  }
};

struct EpiSqPart {  // K-split partial, plain store
  float* buf;
  __device__ __forceinline__ void operator()(int b, int ks, int i, int j, float v) const {
    buf[(size_t)ks * NNNN + (size_t)i * NN + j] = v;
  }
};

struct EpiAggPart {  // 2-way K-split partials (p0 = d_out, p1 = ws)
  float* p0;
  float* p1;
  __device__ __forceinline__ void operator()(int b, int ks, int i, int d, float v) const {
    (ks ? p1 : p0)[(size_t)b * NN * DD + (size_t)i * DD + d] = v;
  }
};

#define LGKM_BARRIER() do { \
  asm volatile("s_waitcnt lgkmcnt(0)" ::: "memory"); \
  __builtin_amdgcn_s_barrier(); \
  asm volatile("" ::: "memory"); } while (0)

template <int MW, bool COMB, typename Epi>
__global__ __launch_bounds__(256, MW) void gemm_pipe(
    const unsigned short* __restrict__ Ap, size_t sA,
    const unsigned short* __restrict__ WtP, const unsigned char* __restrict__ McP,
    const unsigned short* __restrict__ Bp, size_t sB,
    int swz, int ksN, int nit, Epi epi) {
  __shared__ __align__(16) unsigned short As[2 * BM * BK];
  __shared__ __align__(16) unsigned short Bs[2 * BN * BK];
  const int z = blockIdx.z;
  const int b = z / ksN, ks = z - b * ksN;
  const int kbase = ks * nit * BK;
  int bx = blockIdx.x, by = blockIdx.y;
  if (swz) {  // 2x4 rect for per-XCD L2 locality
    int lin = bx + (by << 3);
    int r = lin & 7, s = lin >> 3;
    bx = ((r & 3) << 1) | (s & 1);
    by = ((r >> 2) << 2) | (s >> 1);
  }
  const int tm = bx * BM, tn = by * BN;
  const unsigned short* Ab = Ap + (size_t)b * sA;
  const unsigned short* Bb = Bp + (size_t)b * sB;
  const unsigned short* Wb = COMB ? (WtP + (size_t)b * sA) : nullptr;
  const int tid = threadIdx.x;
  const int w = tid >> 6, l = tid & 63;
  const int lr = l >> 2, lc = l & 3;
  const int fr = l & 15, quad = l >> 4;
  const int moff = (w & 1) * 64, noff = (w >> 1) * 64;
  const int r0 = w * 16 + lr, r1 = (w + 4) * 16 + lr;
  const int kc0 = lc ^ ((r0 >> 1) & 3), kc1 = lc ^ ((r1 >> 1) & 3);
  const size_t ao0 = (size_t)(tm + r0) * NN + kbase + kc0 * 8;
  const size_t ao1 = (size_t)(tm + r1) * NN + kbase + kc1 * 8;
  const size_t bo0 = (size_t)(tn + r0) * NN + kbase + kc0 * 8;
  const size_t bo1 = (size_t)(tn + r1) * NN + kbase + kc1 * 8;
  const int ls0 = r0 * BK + lc * 8, ls1 = r1 * BK + lc * 8;

  unsigned short* const As0 = As;           unsigned short* const As1 = As + BM * BK;
  unsigned short* const Bs0 = Bs;           unsigned short* const Bs1 = Bs + BN * BK;

  f32x4 acc[4][4];
#pragma unroll
  for (int mi = 0; mi < 4; ++mi)
#pragma unroll
    for (int ni = 0; ni < 4; ++ni) acc[mi][ni] = (f32x4){0.f, 0.f, 0.f, 0.f};

  struct RegSet {
    u16x8 a0, a1, b0, b1;
    u16x8 w0, w1;
    unsigned long long m0, m1;
  };
  RegSet R0, R1;  // two NAMED sets — always selected by compile-time control flow

  auto load = [&](RegSet& R, int kt) {
    size_t kk = (size_t)kt * BK;
    R.a0 = *(const u16x8*)(Ab + ao0 + kk);
    R.a1 = *(const u16x8*)(Ab + ao1 + kk);
    R.b0 = *(const u16x8*)(Bb + bo0 + kk);
    R.b1 = *(const u16x8*)(Bb + bo1 + kk);
    if constexpr (COMB) {
      R.w0 = *(const u16x8*)(Wb + ao0 + kk);
      R.w1 = *(const u16x8*)(Wb + ao1 + kk);
      R.m0 = *(const unsigned long long*)(McP + ao0 + kk);
      R.m1 = *(const unsigned long long*)(McP + ao1 + kk);
    }
  };
  auto wr = [&](const RegSet& R, unsigned short* Ad, unsigned short* Bd) {
    if constexpr (COMB) {
      u16x8 f0, f1;
#pragma unroll
      for (int j = 0; j < 8; ++j) {
        float s0 = bf2f(R.a0[j]);
        if ((R.m0 >> (8 * j)) & 1ull) s0 += bf2f(R.w0[j]);
        f0[j] = f2bf(s0);
        float s1 = bf2f(R.a1[j]);
        if ((R.m1 >> (8 * j)) & 1ull) s1 += bf2f(R.w1[j]);
        f1[j] = f2bf(s1);
      }
      *(u16x8*)(Ad + ls0) = f0;
      *(u16x8*)(Ad + ls1) = f1;
    } else {
      *(u16x8*)(Ad + ls0) = R.a0;
      *(u16x8*)(Ad + ls1) = R.a1;
    }
    *(u16x8*)(Bd + ls0) = R.b0;
    *(u16x8*)(Bd + ls1) = R.b1;
  };
  auto compute = [&](const unsigned short* Ad, const unsigned short* Bd) {
    bf16x8 af[4], bfr[4];
#pragma unroll
    for (int mi = 0; mi < 4; ++mi) {
      int r = moff + mi * 16 + fr;
      int kc = quad ^ ((r >> 1) & 3);
      af[mi] = *(const bf16x8*)(Ad + r * BK + kc * 8);
    }
#pragma unroll
    for (int ni = 0; ni < 4; ++ni) {
      int r = noff + ni * 16 + fr;
      int kc = quad ^ ((r >> 1) & 3);
      bfr[ni] = *(const bf16x8*)(Bd + r * BK + kc * 8);
    }
#pragma unroll
    for (int mi = 0; mi < 4; ++mi)
#pragma unroll
      for (int ni = 0; ni < 4; ++ni)
        acc[mi][ni] = __builtin_amdgcn_mfma_f32_16x16x32_bf16(af[mi], bfr[ni], acc[mi][ni], 0, 0, 0);
  };

  // prologue: LDS0<-tile0; R1<-tile1 (in flight); R0<-tile2 (in flight)
  load(R0, 0);
  load(R1, 1);
  wr(R0, As0, Bs0);
  load(R0, 2);
  LGKM_BARRIER();
  // invariant entering pair kt (even): LDS0 = tile kt, R1 = tile kt+1, R0 = tile kt+2
#pragma unroll 1
  for (int kt = 0; kt < nit - 2; kt += 2) {
    compute(As0, Bs0);                     // tile kt
    wr(R1, As1, Bs1);                      // tile kt+1 -> LDS1
    if (kt + 3 < nit) load(R1, kt + 3);
    LGKM_BARRIER();
    compute(As1, Bs1);                     // tile kt+1
    wr(R0, As0, Bs0);                      // tile kt+2 -> LDS0
    if (kt + 4 < nit) load(R0, kt + 4);
    LGKM_BARRIER();
  }
  compute(As0, Bs0);                       // tile nit-2
  wr(R1, As1, Bs1);                        // tile nit-1
  LGKM_BARRIER();
  compute(As1, Bs1);                       // tile nit-1

  // C/D layout: col = lane&15, row = quad*4 + reg
#pragma unroll
  for (int mi = 0; mi < 4; ++mi)
#pragma unroll
    for (int ni = 0; ni < 4; ++ni)
#pragma unroll
      for (int t = 0; t < 4; ++t)
        epi(b, ks, tm + moff + mi * 16 + quad * 4 + t, tn + noff + ni * 16 + fr, acc[mi][ni][t]);
}

// ---------------- gated hop-2 sparse fixup (expected: nnz==0, exits) ----------------
__global__ __launch_bounds__(256) void hop2_fix(const unsigned short* __restrict__ Wp,
    const unsigned short* __restrict__ WpT, const int* __restrict__ nnz,
    const unsigned int* __restrict__ entries, unsigned short* __restrict__ WcombT) {
  int n = *nnz;
  if (n > CAP) n = CAP;
  if (n == 0) return;
  __shared__ float rbuf[256];
  const int b = blockIdx.x;
  const size_t bnn = (size_t)b * NNNN;
  for (int e = blockIdx.y; e < n; e += gridDim.y) {
    unsigned int ent = entries[e];
    int j = ent >> 16, i = ent & 0xFFFF;
    float s = 0.f;
    for (int k = threadIdx.x; k < NN; k += 256) {
      float u = 0.f, v = 0.f;
      const unsigned short* wj  = Wp  + bnn + (size_t)j * NN;
      const unsigned short* wtk = WpT + bnn + (size_t)k * NN;
      const unsigned short* wk  = Wp  + bnn + (size_t)k * NN;
      const unsigned short* wti = WpT + bnn + (size_t)i * NN;
      for (int t = 0; t < NN; ++t) {
        u += bf2f(wj[t]) * bf2f(wtk[t]);
        v += bf2f(wk[t]) * bf2f(wti[t]);
      }
      s += u * v;
    }
    rbuf[threadIdx.x] = s;
    __syncthreads();
    for (int off = 128; off > 0; off >>= 1) {
      if (threadIdx.x < off) rbuf[threadIdx.x] += rbuf[threadIdx.x + off];
      __syncthreads();
    }
    if (threadIdx.x == 0) {
      size_t idx = bnn + (size_t)i * NN + j;
      WcombT[idx] = f2bf(bf2f(WcombT[idx]) + rbuf[0]);
    }
    __syncthreads();
  }
}

// ---------------- fused (sum 2 agg partials) + Linear + residual + LayerNorm ----------------
#define FROWS 16
__global__ __launch_bounds__(256) void fused_out(const float* __restrict__ a0p,
    const float* __restrict__ a1p, const float* __restrict__ x,
    const float* __restrict__ W, const float* __restrict__ bias,
    const float* __restrict__ g2, const float* __restrict__ bsh,
    float* __restrict__ out) {
  __shared__ unsigned short Wl[128 * 136];
  __shared__ float ar[256];
  __shared__ float wred[8];
  const int tid = threadIdx.x;
  for (int e = tid; e < 16384; e += 256) Wl[(e >> 7) * 136 + (e & 127)] = f2bf(W[e]);
  const int half = tid >> 7, o = tid & 127;
  const int w = tid >> 6, lane = tid & 63;
  const float bo = bias[o], go = g2[o], b2o = bsh[o];
  const size_t row0 = (size_t)blockIdx.x * FROWS;
  size_t rb = row0 * DD;
  float av = a0p[rb + tid] + a1p[rb + tid];   // prefetched row pair
  float xv = x[rb + tid];
  __syncthreads();  // Wl ready
  for (int rr = 0; rr < FROWS; rr += 2) {
    ar[tid] = av;
    const float xcur = xv;
    const size_t rbc = (row0 + rr) * DD;
    __syncthreads();  // ar ready
    if (rr + 2 < FROWS) {
      size_t rb2 = (row0 + rr + 2) * DD;
      av = a0p[rb2 + tid] + a1p[rb2 + tid];
      xv = x[rb2 + tid];
    }
    float hv = bo + xcur;
    const unsigned short* wrow = &Wl[o * 136];
    const float* arow = &ar[half * 128];
#pragma unroll
    for (int d8 = 0; d8 < 16; ++d8) {
      bf16x8 wv = *(const bf16x8*)(wrow + d8 * 8);
#pragma unroll
      for (int t = 0; t < 8; ++t) hv += (float)wv[t] * arow[d8 * 8 + t];
    }
    float s = hv, q = hv * hv;
#pragma unroll
    for (int off = 32; off > 0; off >>= 1) {
      s += __shfl_xor(s, off);
      q += __shfl_xor(q, off);
    }
    if (lane == 0) { wred[w] = s; wred[4 + w] = q; }
    __syncthreads();  // wred ready (also gates ar overwrite next iter)
    float st = wred[half * 2] + wred[half * 2 + 1];
    float qt = wred[4 + half * 2] + wred[4 + half * 2 + 1];
    float mean = st * (1.0f / 128.0f);
    float var = (qt - 128.0f * mean * mean) * (1.0f / 127.0f);
    var = fmaxf(var, 0.0f);
    float stdv = sqrtf(var);
    out[rbc + tid] = go * (hv - mean) / (stdv + EPSF) + b2o;
  }
}

// ---------------- launch ----------------
extern "C" void kernel_launch(void* const* d_in, const int* in_sizes, int n_in,
                              void* d_out, int out_size, void* d_ws, size_t ws_size,
                              hipStream_t stream) {
  (void)in_sizes; (void)n_in; (void)out_size; (void)ws_size;
  const float* x    = (const float*)d_in[0];
  const float* adjw = (const float*)d_in[1];
  const float* adj  = (const float*)d_in[2];
  const float* W    = (const float*)d_in[3];
  const float* bias = (const float*)d_in[4];
  const float* a2   = (const float*)d_in[5];
  const float* b2   = (const float*)d_in[6];
  float* out = (float*)d_out;

  char* ws = (char*)d_ws;
  const size_t MB = 1048576;
  unsigned short* Wp_bf   = (unsigned short*)(ws);             // 64 MB
  unsigned short* WpT_bf  = (unsigned short*)(ws + 64 * MB);   // 64 MB
  unsigned short* WcombT  = (unsigned short*)(ws + 128 * MB);  // 64 MB
  unsigned short* xT_bf   = (unsigned short*)(ws + 192 * MB);  // 8 MB
  unsigned short* adj_bf  = (unsigned short*)(ws + 200 * MB);  // 2 MB
  unsigned short* adjT_bf = (unsigned short*)(ws + 202 * MB);  // 2 MB
  unsigned short* A2_bf   = (unsigned short*)(ws + 204 * MB);  // 2 MB
  unsigned short* A2T_bf  = (unsigned short*)(ws + 206 * MB);  // 2 MB
  float* sqpart           = (float*)(ws + 208 * MB);           // 16 MB (4 partials)
  // agg partial 1 overlaps the adj/A2/sqpart region (all consumed before agg gemm)
  float* agg1             = (float*)(ws + 200 * MB);           // 16 MB
  unsigned char* mcode    = (unsigned char*)(ws + 224 * MB);   // 1 MB
  unsigned int* entries   = (unsigned int*)(ws + 225 * MB);    // 64 KB
  int* nnz2               = (int*)(ws + 226 * MB);             // 4 B
  float* agg0 = out;  // d_out doubles as agg partial 0

  hipMemsetAsync(nnz2, 0, 4, stream);

  dim3 blk32(32, 8, 1);
  convert_wp<<<dim3(16, 16, 32), 256, 0, stream>>>(adjw, Wp_bf, WpT_bf);
  convert_x<<<dim3(4, 32, 32), blk32, 0, stream>>>(x, xT_bf);
  mask0cvt<<<dim3(32, 32, 1), blk32, 0, stream>>>(adj, mcode, adj_bf, adjT_bf);

  // A^2: K-split 4, exact integer partials, plain stores
  gemm_pipe<3, false><<<dim3(8, 8, 4), 256, 0, stream>>>(
      adj_bf, (size_t)0, nullptr, nullptr, adjT_bf, (size_t)0, 0, 4, 8,
      EpiSqPart{sqpart});
  scan_a2<<<dim3(32, 32, 1), blk32, 0, stream>>>(sqpart, A2_bf, A2T_bf, mcode);
  // A^4: K-split 4 (A^2 ints < 256 exact in bf16)
  gemm_pipe<3, false><<<dim3(8, 8, 4), 256, 0, stream>>>(
      A2_bf, (size_t)0, nullptr, nullptr, A2T_bf, (size_t)0, 0, 4, 8,
      EpiSqPart{sqpart});
  scan_a4<<<dim3(4096, 1, 1), 256, 0, stream>>>(sqpart, entries, nnz2);

  // big batched gemm: WcombT = mask2 .* (Wp^2)^T
  gemm_pipe<3, false><<<dim3(8, 8, 32), 256, 0, stream>>>(
      WpT_bf, NNNN, nullptr, nullptr, Wp_bf, NNNN, 1, 1, NN / BK,
      EpiWcomb{mcode, WcombT});

  hop2_fix<<<dim3(32, 8, 1), 256, 0, stream>>>(Wp_bf, WpT_bf, nnz2, entries, WcombT);

  // agg = (WcombT + mask1^T.*WpT) @ x — K-split 2 partials (fold in staging)
  gemm_pipe<2, true><<<dim3(8, 1, 64), 256, 0, stream>>>(
      WcombT, NNNN, WpT_bf, mcode, xT_bf, (size_t)DD * NN, 0, 2, 16,
      EpiAggPart{agg0, agg1});

  fused_out<<<dim3(2048, 1, 1), 256, 0, stream>>>(agg0, agg1, x, W, bias, a2, b2, out);
}